// Round 3
// baseline (194.870 us; speedup 1.0000x reference)
//
#include <hip/hip_runtime.h>

#define S0LEN 8192
#define L1LEN 4099   // (8192+7)/2
#define L2LEN 2053   // (4099+7)/2
#define NROWS 2048
#define NT    256    // transpose kernels
#define NT2   512    // denoise kernel

// db4 filters (derived from reference _REC_LO)
constexpr float DEC_LO[8] = {
  -0.010597401784997278f,  0.032883011666982945f,  0.030841381835986965f,
  -0.18703481171888114f,  -0.02798376941698385f,   0.6308807679295904f,
   0.7148465705525415f,    0.23037781330885523f };
constexpr float DEC_HI[8] = {
  -0.23037781330885523f,   0.7148465705525415f,   -0.6308807679295904f,
  -0.02798376941698385f,   0.18703481171888114f,   0.030841381835986965f,
  -0.032883011666982945f, -0.010597401784997278f };
constexpr float REC_LO[8] = {
   0.23037781330885523f,   0.7148465705525415f,    0.6308807679295904f,
  -0.02798376941698385f,  -0.18703481171888114f,   0.030841381835986965f,
   0.032883011666982945f, -0.010597401784997278f };
constexpr float REC_HI[8] = {
  -0.010597401784997278f, -0.032883011666982945f,  0.030841381835986965f,
   0.18703481171888114f,  -0.02798376941698385f,  -0.6308807679295904f,
   0.7148465705525415f,   -0.23037781330885523f };

__device__ __forceinline__ int refl(int m, int n) {
  m = (m < 0) ? (-1 - m) : m;
  m = (m >= n) ? (2 * n - 1 - m) : m;
  return m;
}

__device__ __forceinline__ float softf(float c, float t) {
  float m = fmaxf(fabsf(c) - t, 0.0f);
  return copysignf(m, c);
}

// one DWT stage: src[n_in] -> outA[n_out], outD[n_out]
// interior outputs use aligned float2 LDS loads (byte addr 8*(i-3), provably 8B aligned)
__device__ __forceinline__ void dwt_stage(const float* __restrict__ src, int n_in,
                                          float* __restrict__ outA,
                                          float* __restrict__ outD,
                                          int n_out, int t) {
  const float2* s2 = reinterpret_cast<const float2*>(src);
  const int ihi = (n_in - 2) >> 1;   // max i with 2i+1 <= n_in-1
  for (int i = t; i < n_out; i += NT2) {
    float f[8];
    if (i >= 3 && i <= ihi) {
      const float2 v0 = s2[i - 3], v1 = s2[i - 2], v2 = s2[i - 1], v3 = s2[i];
      f[0] = v0.x; f[1] = v0.y; f[2] = v1.x; f[3] = v1.y;
      f[4] = v2.x; f[5] = v2.y; f[6] = v3.x; f[7] = v3.y;
    } else {
      const int base = 2 * i - 6;   // f[q] = src[2i-6+q]
#pragma unroll
      for (int q = 0; q < 8; ++q) f[q] = src[refl(base + q, n_in)];
    }
    float aa = 0.0f, dd = 0.0f;
#pragma unroll
    for (int q = 0; q < 8; ++q) {   // coefficient index j = 7-q
      aa = fmaf(DEC_LO[7 - q], f[q], aa);
      dd = fmaf(DEC_HI[7 - q], f[q], dd);
    }
    outA[i] = aa;
    outD[i] = dd;
  }
}

// K1: x (32, 8192, 64) -> xt (2048, 8192), row r = b*64+f
__global__ void __launch_bounds__(NT)
k_transpose_fwd(const float* __restrict__ x, float* __restrict__ xt) {
  const int b  = blockIdx.y;
  const int s0 = blockIdx.x * 64;
  __shared__ float tile[64][65];
  const int t = threadIdx.x;
  const float* xb = x + (size_t)b * S0LEN * 64;

  const int c4 = t & 15;   // f4 col
  const int sl = t >> 4;   // 0..15
#pragma unroll
  for (int k = 0; k < 4; ++k) {
    const int s = sl + 16 * k;
    const float4 v = *reinterpret_cast<const float4*>(xb + (size_t)(s0 + s) * 64 + 4 * c4);
    tile[s][4 * c4 + 0] = v.x; tile[s][4 * c4 + 1] = v.y;
    tile[s][4 * c4 + 2] = v.z; tile[s][4 * c4 + 3] = v.w;
  }
  __syncthreads();

  const int m = t & 15;    // s4
  const int f = t >> 4;    // 0..15
#pragma unroll
  for (int k = 0; k < 4; ++k) {
    const int ff = f + 16 * k;
    float4 v;
    v.x = tile[4 * m + 0][ff]; v.y = tile[4 * m + 1][ff];
    v.z = tile[4 * m + 2][ff]; v.w = tile[4 * m + 3][ff];
    *reinterpret_cast<float4*>(xt + (size_t)(b * 64 + ff) * S0LEN + s0 + 4 * m) = v;
  }
}

// K2: per-row denoise, in place on ws row
__global__ void __launch_bounds__(NT2)
k_denoise(float* __restrict__ ws) {
  const int r = blockIdx.x;
  float* row = ws + (size_t)r * S0LEN;

  __shared__ alignas(16) float sA[8208];   // x(8192) -> a2|d2(2x2053) | rec1/uabs(4099) @ 4106
  __shared__ alignas(16) float sa1[4100];
  __shared__ alignas(16) float sd1[4100];
  __shared__ unsigned histp[8 * 256];      // per-wave private histograms
  __shared__ unsigned wsum[4];
  __shared__ int sh_bin, sh_k;
  const int t = threadIdx.x;

  // 1. load row (coalesced float4)
  {
    const float4* src4 = reinterpret_cast<const float4*>(row);
    float4* dst4 = reinterpret_cast<float4*>(sA);
    for (int k = t; k < S0LEN / 4; k += NT2) dst4[k] = src4[k];
  }
  __syncthreads();

  // 2. level-1 DWT: x(8192) -> a1,d1 (4099)
  dwt_stage(sA, S0LEN, sa1, sd1, L1LEN, t);
  __syncthreads();

  // 3. level-2 DWT: a1(4099) -> a2,d2 (2053), overwriting sA (x dead)
  dwt_stage(sa1, L1LEN, sA, sA + L2LEN, L2LEN, t);
  __syncthreads();

  // 4. exact median of |d1| (4099 elems, 0-indexed rank 2049), 4x radix-256 select.
  //    Private per-wave histograms + |d1| bit patterns cached in rec1 region.
  unsigned* ud = reinterpret_cast<unsigned*>(sA + 2 * L2LEN);  // free until step 6
  unsigned prefval = 0u, himask = 0u;
  int k = 2049;
#pragma unroll
  for (int pass = 0; pass < 4; ++pass) {
    const int shift = 24 - 8 * pass;
    for (int i = t; i < 8 * 256; i += NT2) histp[i] = 0u;
    __syncthreads();
    unsigned* myh = histp + (t >> 6) * 256;
    if (pass == 0) {
      for (int i = t; i < L1LEN; i += NT2) {
        const unsigned u = __float_as_uint(fabsf(sd1[i]));
        ud[i] = u;
        atomicAdd(&myh[u >> 24], 1u);
      }
    } else {
      for (int i = t; i < L1LEN; i += NT2) {
        const unsigned u = ud[i];
        if ((u & himask) == prefval) atomicAdd(&myh[(u >> shift) & 255u], 1u);
      }
    }
    __syncthreads();
    // parallel merge + prefix scan + unique-winner select (threads 0..255)
    unsigned c = 0u, incl = 0u;
    if (t < 256) {
#pragma unroll
      for (int w = 0; w < 8; ++w) c += histp[w * 256 + t];
      incl = c;
#pragma unroll
      for (int d = 1; d < 64; d <<= 1) {
        const unsigned n = __shfl_up(incl, d, 64);
        if ((t & 63) >= d) incl += n;
      }
      if ((t & 63) == 63) wsum[t >> 6] = incl;
    }
    __syncthreads();
    if (t < 256) {
      unsigned base = 0u;
      for (int w = 0; w < (t >> 6); ++w) base += wsum[w];
      incl += base;
      if ((unsigned)k < incl && (unsigned)k >= incl - c) {
        sh_bin = t; sh_k = k - (int)(incl - c);
      }
    }
    __syncthreads();
    prefval |= ((unsigned)sh_bin) << shift;
    himask  |= 255u << shift;
    k = sh_k;
    // next pass's sh_* writes are separated from these reads by two barriers
  }
  const float median = __uint_as_float(prefval);
  const float thr = (median / 0.6745f) * sqrtf(2.0f * logf(8192.0f));

  // 5. soft-threshold a2,d2 (contiguous) and d1, in place
  for (int i = t; i < 2 * L2LEN; i += NT2) sA[i] = softf(sA[i], thr);
  for (int i = t; i < L1LEN; i += NT2)     sd1[i] = softf(sd1[i], thr);
  __syncthreads();

  // 6. iDWT level-2: (a2s,d2s) -> rec1[0..4098]; thread computes pair (2p, 2p+1)
  {
    const float* a2 = sA;
    const float* d2 = sA + L2LEN;
    float* rec1 = sA + 2 * L2LEN;
    for (int p = t; p <= 2049; p += NT2) {
      float av[4], dv[4];
#pragma unroll
      for (int c2 = 0; c2 < 4; ++c2) { av[c2] = a2[p + c2]; dv[c2] = d2[p + c2]; }
      float e = 0.0f, o = 0.0f;
#pragma unroll
      for (int u = 0; u < 4; ++u) {        // m = p+3-u -> local idx 3-u
        e = fmaf(av[3 - u], REC_LO[2 * u],     e);
        e = fmaf(dv[3 - u], REC_HI[2 * u],     e);
        o = fmaf(av[3 - u], REC_LO[2 * u + 1], o);
        o = fmaf(dv[3 - u], REC_HI[2 * u + 1], o);
      }
      rec1[2 * p] = e;
      if (2 * p + 1 < L1LEN) rec1[2 * p + 1] = o;
    }
  }
  __syncthreads();

  // 7. iDWT level-1: (rec1, d1s) -> out(8192); thread computes quad 4q..4q+3
  {
    const float* rec1 = sA + 2 * L2LEN;
    for (int q = t; q < S0LEN / 4; q += NT2) {
      float ra[5], rd[5];
#pragma unroll
      for (int c2 = 0; c2 < 5; ++c2) { ra[c2] = rec1[2 * q + c2]; rd[c2] = sd1[2 * q + c2]; }
      float4 v;
      float acc;
      // i = 4q+0: p=2q, o=0 ; local a-idx = 3-u
      acc = 0.0f;
#pragma unroll
      for (int u = 0; u < 4; ++u) {
        acc = fmaf(ra[3 - u], REC_LO[2 * u], acc);
        acc = fmaf(rd[3 - u], REC_HI[2 * u], acc);
      }
      v.x = acc;
      // i = 4q+1: p=2q, o=1
      acc = 0.0f;
#pragma unroll
      for (int u = 0; u < 4; ++u) {
        acc = fmaf(ra[3 - u], REC_LO[2 * u + 1], acc);
        acc = fmaf(rd[3 - u], REC_HI[2 * u + 1], acc);
      }
      v.y = acc;
      // i = 4q+2: p=2q+1, o=0 ; local idx 4-u
      acc = 0.0f;
#pragma unroll
      for (int u = 0; u < 4; ++u) {
        acc = fmaf(ra[4 - u], REC_LO[2 * u], acc);
        acc = fmaf(rd[4 - u], REC_HI[2 * u], acc);
      }
      v.z = acc;
      // i = 4q+3: p=2q+1, o=1
      acc = 0.0f;
#pragma unroll
      for (int u = 0; u < 4; ++u) {
        acc = fmaf(ra[4 - u], REC_LO[2 * u + 1], acc);
        acc = fmaf(rd[4 - u], REC_HI[2 * u + 1], acc);
      }
      v.w = acc;
      reinterpret_cast<float4*>(row)[q] = v;
    }
  }
}

// K3: xt (2048, 8192) -> out (32, 8192, 64)
__global__ void __launch_bounds__(NT)
k_transpose_bwd(const float* __restrict__ xt, float* __restrict__ out) {
  const int b  = blockIdx.y;
  const int s0 = blockIdx.x * 64;
  __shared__ float tile[64][65];   // tile[f][s]
  const int t = threadIdx.x;

  const int m = t & 15;    // s4
  const int f = t >> 4;    // 0..15
#pragma unroll
  for (int k = 0; k < 4; ++k) {
    const int ff = f + 16 * k;
    const float4 v = *reinterpret_cast<const float4*>(xt + (size_t)(b * 64 + ff) * S0LEN + s0 + 4 * m);
    tile[ff][4 * m + 0] = v.x; tile[ff][4 * m + 1] = v.y;
    tile[ff][4 * m + 2] = v.z; tile[ff][4 * m + 3] = v.w;
  }
  __syncthreads();

  float* ob = out + (size_t)b * S0LEN * 64;
  const int c4 = t & 15;   // f4
  const int sl = t >> 4;   // 0..15
#pragma unroll
  for (int k = 0; k < 4; ++k) {
    const int s = sl + 16 * k;
    float4 v;
    v.x = tile[4 * c4 + 0][s]; v.y = tile[4 * c4 + 1][s];
    v.z = tile[4 * c4 + 2][s]; v.w = tile[4 * c4 + 3][s];
    *reinterpret_cast<float4*>(ob + (size_t)(s0 + s) * 64 + 4 * c4) = v;
  }
}

extern "C" void kernel_launch(void* const* d_in, const int* in_sizes, int n_in,
                              void* d_out, int out_size, void* d_ws, size_t ws_size,
                              hipStream_t stream) {
  (void)in_sizes; (void)n_in; (void)out_size; (void)ws_size;
  const float* x = (const float*)d_in[0];
  float* out = (float*)d_out;
  float* ws  = (float*)d_ws;   // needs 2048*8192*4 = 64 MB

  const dim3 gT(S0LEN / 64, 32);

  hipLaunchKernelGGL(k_transpose_fwd, gT, dim3(NT), 0, stream, x, ws);
  hipLaunchKernelGGL(k_denoise, dim3(NROWS), dim3(NT2), 0, stream, ws);
  hipLaunchKernelGGL(k_transpose_bwd, gT, dim3(NT), 0, stream, ws, out);
}

// Round 5
// 189.344 us; speedup vs baseline: 1.0292x; 1.0292x over previous
//
#include <hip/hip_runtime.h>

#define S0LEN 8192
#define L1LEN 4099   // (8192+7)/2
#define L2LEN 2053   // (4099+7)/2
#define NROWS 2048
#define NTT   512    // transpose kernels
#define NT2   512    // denoise kernel

// db4 filters (derived from reference _REC_LO)
constexpr float DEC_LO[8] = {
  -0.010597401784997278f,  0.032883011666982945f,  0.030841381835986965f,
  -0.18703481171888114f,  -0.02798376941698385f,   0.6308807679295904f,
   0.7148465705525415f,    0.23037781330885523f };
constexpr float DEC_HI[8] = {
  -0.23037781330885523f,   0.7148465705525415f,   -0.6308807679295904f,
  -0.02798376941698385f,   0.18703481171888114f,   0.030841381835986965f,
  -0.032883011666982945f, -0.010597401784997278f };
constexpr float REC_LO[8] = {
   0.23037781330885523f,   0.7148465705525415f,    0.6308807679295904f,
  -0.02798376941698385f,  -0.18703481171888114f,   0.030841381835986965f,
   0.032883011666982945f, -0.010597401784997278f };
constexpr float REC_HI[8] = {
  -0.010597401784997278f, -0.032883011666982945f,  0.030841381835986965f,
   0.18703481171888114f,  -0.02798376941698385f,  -0.6308807679295904f,
   0.7148465705525415f,   -0.23037781330885523f };

__device__ __forceinline__ int refl(int m, int n) {
  m = (m < 0) ? (-1 - m) : m;
  m = (m >= n) ? (2 * n - 1 - m) : m;
  return m;
}

__device__ __forceinline__ float softf(float c, float t) {
  float m = fmaxf(fabsf(c) - t, 0.0f);
  return copysignf(m, c);
}

// DWT pair (outputs 2p, 2p+1) from 10-float window w = src[4p-6 .. 4p+3],
// fetched as aligned b64 + b128 + b128 (elem idx e2 float2, e4a/e4b float4).
__device__ __forceinline__ void dwt_pair_vec(const float* __restrict__ buf,
                                             int e2, int e4a, int e4b,
                                             float& ae, float& de, float& ao, float& dd) {
  const float2 w01 = reinterpret_cast<const float2*>(buf)[e2];
  const float4 w25 = reinterpret_cast<const float4*>(buf)[e4a];
  const float4 w69 = reinterpret_cast<const float4*>(buf)[e4b];
  const float w[10] = {w01.x, w01.y, w25.x, w25.y, w25.z, w25.w,
                       w69.x, w69.y, w69.z, w69.w};
  ae = de = ao = dd = 0.f;
#pragma unroll
  for (int q = 0; q < 8; ++q) {   // out[i] += DEC[7-q] * x[2i-6+q]
    ae = fmaf(DEC_LO[7 - q], w[q],     ae);
    de = fmaf(DEC_HI[7 - q], w[q],     de);
    ao = fmaf(DEC_LO[7 - q], w[q + 2], ao);
    dd = fmaf(DEC_HI[7 - q], w[q + 2], dd);
  }
}

// scalar single output i with symmetric reflection; buf holds x[gbase..]
__device__ __forceinline__ void dwt_scalar(const float* __restrict__ buf, int gbase,
                                           int i, int n, float& a, float& d) {
  a = d = 0.f;
#pragma unroll
  for (int q = 0; q < 8; ++q) {
    const float v = buf[refl(2 * i - 6 + q, n) - gbase];
    a = fmaf(DEC_LO[7 - q], v, a);
    d = fmaf(DEC_HI[7 - q], v, d);
  }
}

// iDWT quad: outputs (4q..4q+3) from w = a[2q..2q+4], v = d[2q..2q+4]
__device__ __forceinline__ float4 idwt_quad(const float* __restrict__ w,
                                            const float* __restrict__ v) {
  float4 o; float acc;
  acc = 0.f;
#pragma unroll
  for (int u = 0; u < 4; ++u) { acc = fmaf(w[3-u], REC_LO[2*u],   acc); acc = fmaf(v[3-u], REC_HI[2*u],   acc); }
  o.x = acc;
  acc = 0.f;
#pragma unroll
  for (int u = 0; u < 4; ++u) { acc = fmaf(w[3-u], REC_LO[2*u+1], acc); acc = fmaf(v[3-u], REC_HI[2*u+1], acc); }
  o.y = acc;
  acc = 0.f;
#pragma unroll
  for (int u = 0; u < 4; ++u) { acc = fmaf(w[4-u], REC_LO[2*u],   acc); acc = fmaf(v[4-u], REC_HI[2*u],   acc); }
  o.z = acc;
  acc = 0.f;
#pragma unroll
  for (int u = 0; u < 4; ++u) { acc = fmaf(w[4-u], REC_LO[2*u+1], acc); acc = fmaf(v[4-u], REC_HI[2*u+1], acc); }
  o.w = acc;
  return o;
}

// ---- K1: x (32, 8192, 64) -> xt (2048, 8192); block = 64f x 256s tile ----
// LDS tile [f][s^swz(f)], swz(f) = 4*((f>>2)&7): conflict-free both sides.
__global__ void __launch_bounds__(NTT)
k_transpose_fwd(const float* __restrict__ x, float* __restrict__ xt) {
  const int b  = blockIdx.y;
  const int s0 = blockIdx.x * 256;
  __shared__ float tile[64][256];
  const int t = threadIdx.x;
  const int lane = t & 63;
  const int wv = t >> 6;

  const float* src = x + ((size_t)b * S0LEN + s0) * 64;   // 64KB contiguous
  float4 rg[8];
#pragma unroll
  for (int k = 0; k < 8; ++k)
    rg[k] = reinterpret_cast<const float4*>(src)[t + NTT * k];
#pragma unroll
  for (int k = 0; k < 8; ++k) {
    const int n  = t + NTT * k;
    const int s  = n >> 4;          // 0..255
    const int fg = n & 15;          // float4 group along f
    const int sc = s ^ (4 * (fg & 7));
    tile[4 * fg + 0][sc] = rg[k].x;
    tile[4 * fg + 1][sc] = rg[k].y;
    tile[4 * fg + 2][sc] = rg[k].z;
    tile[4 * fg + 3][sc] = rg[k].w;
  }
  __syncthreads();
#pragma unroll
  for (int j = 0; j < 8; ++j) {
    const int f = 8 * wv + j;
    const int swz = 4 * ((f >> 2) & 7);
    const float4 v = *reinterpret_cast<const float4*>(&tile[f][(4 * lane) ^ swz]);
    reinterpret_cast<float4*>(xt + (size_t)(b * 64 + f) * S0LEN + s0)[lane] = v;  // 1KB/wave-instr
  }
}

// ---- K2: per-row denoise, in place on ws row; 3 blocks/CU ----
__global__ void __launch_bounds__(NT2, 6)
k_denoise(float* __restrict__ ws) {
  const int r = blockIdx.x;
  float* row = ws + (size_t)r * S0LEN;

  __shared__ alignas(16) float X[4112];   // x chunk; later a2[0..2052] | d2 @2056..4108
  __shared__ alignas(16) float A[4100];   // a1; later rec1[0..4098]
  __shared__ alignas(16) float D[4100];   // d1 (raw; soft applied on the fly)
  __shared__ unsigned hist[1024];         // 4 histograms (wave-pairs)
  __shared__ unsigned wsum[4];
  __shared__ int sh_bin, sh_k;
  const int t = threadIdx.x;

  // chunk0 load: x[0..4107]
  {
    const float4* s4 = reinterpret_cast<const float4*>(row);
    float4* d4 = reinterpret_cast<float4*>(X);
    for (int j = t; j < 1027; j += NT2) d4[j] = s4[j];
  }
  __syncthreads();

  // DWT1 chunk0: pairs p=0..1023 -> outputs 0..2047 (vector for p>=2)
  for (int p = t; p < 1024; p += NT2) {
    float ae, de, ao, dd;
    if (p >= 2) dwt_pair_vec(X, 2 * p - 3, p - 1, p, ae, de, ao, dd);
    else { dwt_scalar(X, 0, 2 * p, S0LEN, ae, de); dwt_scalar(X, 0, 2 * p + 1, S0LEN, ao, dd); }
    reinterpret_cast<float2*>(A)[p] = make_float2(ae, ao);
    reinterpret_cast<float2*>(D)[p] = make_float2(de, dd);
  }
  __syncthreads();

  // chunk1 load: x[4088..8191] -> X[0..4103]  (base 4088 keeps b128 alignment)
  {
    const float4* s4 = reinterpret_cast<const float4*>(row) + 1022;
    float4* d4 = reinterpret_cast<float4*>(X);
    for (int j = t; j < 1026; j += NT2) d4[j] = s4[j];
  }
  __syncthreads();

  // DWT1 chunk1: pairs p=1024..2048 -> outputs 2048..4097 (vector for p<2048), + single 4098
  for (int p0 = t; p0 < 1025; p0 += NT2) {
    const int p = 1024 + p0;
    float ae, de, ao, dd;
    if (p < 2048) dwt_pair_vec(X, 2 * p - 2047, p - 1023, p - 1022, ae, de, ao, dd);
    else { dwt_scalar(X, 4088, 2 * p, S0LEN, ae, de); dwt_scalar(X, 4088, 2 * p + 1, S0LEN, ao, dd); }
    reinterpret_cast<float2*>(A)[p] = make_float2(ae, ao);
    reinterpret_cast<float2*>(D)[p] = make_float2(de, dd);
  }
  if (t == 0) {
    float a, d; dwt_scalar(X, 4088, 4098, S0LEN, a, d);
    A[4098] = a; D[4098] = d;
  }
  __syncthreads();

  // DWT2: A(4099) -> a2=X[0..2052], d2=X[2056..4108]; pairs 0..1025 (vector 2..1023) + single 2052
  for (int p = t; p < 1026; p += NT2) {
    float ae, de, ao, dd;
    if (p >= 2 && p <= 1023) dwt_pair_vec(A, 2 * p - 3, p - 1, p, ae, de, ao, dd);
    else { dwt_scalar(A, 0, 2 * p, L1LEN, ae, de); dwt_scalar(A, 0, 2 * p + 1, L1LEN, ao, dd); }
    reinterpret_cast<float2*>(X)[p] = make_float2(ae, ao);
    reinterpret_cast<float2*>(X)[1028 + p] = make_float2(de, dd);
  }
  if (t == 1) {
    float a, d; dwt_scalar(A, 0, 2052, L1LEN, a, d);
    X[2052] = a; X[2056 + 2052] = d;
  }
  __syncthreads();

  // exact median of |D| (4099 elems, 0-indexed rank 2049), 4x radix-256 select
  unsigned prefval = 0u, himask = 0u;
  int kk = 2049;
  for (int pass = 0; pass < 4; ++pass) {
    const int shift = 24 - 8 * pass;
    for (int i = t; i < 1024; i += NT2) hist[i] = 0u;
    __syncthreads();
    unsigned* myh = hist + ((t >> 7) << 8);   // wave-pair private histogram
    for (int i = t; i < L1LEN; i += NT2) {
      const unsigned u = __float_as_uint(fabsf(D[i]));
      if ((u & himask) == prefval) atomicAdd(&myh[(u >> shift) & 255u], 1u);
    }
    __syncthreads();
    unsigned c = 0u, incl = 0u;
    if (t < 256) {
      c = hist[t] + hist[t + 256] + hist[t + 512] + hist[t + 768];
      incl = c;
#pragma unroll
      for (int dlt = 1; dlt < 64; dlt <<= 1) {
        const unsigned nn = __shfl_up(incl, dlt, 64);
        if ((t & 63) >= dlt) incl += nn;
      }
      if ((t & 63) == 63) wsum[t >> 6] = incl;
    }
    __syncthreads();
    if (t < 256) {
      unsigned base = 0u;
      for (int w = 0; w < (t >> 6); ++w) base += wsum[w];
      incl += base;
      if ((unsigned)kk < incl && (unsigned)kk >= incl - c) {
        sh_bin = t; sh_k = kk - (int)(incl - c);
      }
    }
    __syncthreads();
    prefval |= ((unsigned)sh_bin) << shift;
    himask  |= 255u << shift;
    kk = sh_k;
  }
  const float thr = (__uint_as_float(prefval) / 0.6745f) * sqrtf(2.0f * logf(8192.0f));

  // iDWT2 with on-the-fly soft(a2), soft(d2): -> rec1 = A[0..4098]
  {
    const float* a2 = X;
    const float* d2 = X + 2056;
    for (int q = t; q < 1024; q += NT2) {
      const float2 a0 = reinterpret_cast<const float2*>(a2)[q];
      const float2 a1 = reinterpret_cast<const float2*>(a2)[q + 1];
      const float  a4 = a2[2 * q + 4];
      const float2 b0 = reinterpret_cast<const float2*>(d2)[q];
      const float2 b1 = reinterpret_cast<const float2*>(d2)[q + 1];
      const float  b4 = d2[2 * q + 4];
      const float w[5] = {softf(a0.x, thr), softf(a0.y, thr), softf(a1.x, thr),
                          softf(a1.y, thr), softf(a4, thr)};
      const float v[5] = {softf(b0.x, thr), softf(b0.y, thr), softf(b1.x, thr),
                          softf(b1.y, thr), softf(b4, thr)};
      reinterpret_cast<float4*>(A)[q] = idwt_quad(w, v);
    }
    if (t < 3) {   // tail outputs 4096..4098
      const int i = 4096 + t, p = i >> 1, oo = i & 1;
      float acc = 0.f;
#pragma unroll
      for (int u = 0; u < 4; ++u) {
        acc = fmaf(softf(a2[p + 3 - u], thr), REC_LO[2 * u + oo], acc);
        acc = fmaf(softf(d2[p + 3 - u], thr), REC_HI[2 * u + oo], acc);
      }
      A[i] = acc;
    }
  }
  __syncthreads();

  // iDWT1 with on-the-fly soft(d1): (rec1=A raw, D soft) -> row (float4 stores)
  for (int q = t; q < 2048; q += NT2) {
    const float2 r0 = reinterpret_cast<const float2*>(A)[q];
    const float2 r1 = reinterpret_cast<const float2*>(A)[q + 1];
    const float  r4 = A[2 * q + 4];
    const float2 e0 = reinterpret_cast<const float2*>(D)[q];
    const float2 e1 = reinterpret_cast<const float2*>(D)[q + 1];
    const float  e4 = D[2 * q + 4];
    const float w[5] = {r0.x, r0.y, r1.x, r1.y, r4};
    const float v[5] = {softf(e0.x, thr), softf(e0.y, thr), softf(e1.x, thr),
                        softf(e1.y, thr), softf(e4, thr)};
    reinterpret_cast<float4*>(row)[q] = idwt_quad(w, v);
  }
}

// ---- K3: xt (2048, 8192) -> out (32, 8192, 64); mirror of K1 ----
__global__ void __launch_bounds__(NTT)
k_transpose_bwd(const float* __restrict__ xt, float* __restrict__ out) {
  const int b  = blockIdx.y;
  const int s0 = blockIdx.x * 256;
  __shared__ float tile[64][256];
  const int t = threadIdx.x;
  const int lane = t & 63;
  const int wv = t >> 6;

#pragma unroll
  for (int j = 0; j < 8; ++j) {
    const int f = 8 * wv + j;
    const int swz = 4 * ((f >> 2) & 7);
    const float4 v = reinterpret_cast<const float4*>(xt + (size_t)(b * 64 + f) * S0LEN + s0)[lane];
    *reinterpret_cast<float4*>(&tile[f][(4 * lane) ^ swz]) = v;
  }
  __syncthreads();

  float* dst = out + ((size_t)b * S0LEN + s0) * 64;   // 64KB contiguous
#pragma unroll
  for (int k = 0; k < 8; ++k) {
    const int n  = t + NTT * k;
    const int s  = n >> 4;
    const int fg = n & 15;
    const int sc = s ^ (4 * (fg & 7));
    float4 v;
    v.x = tile[4 * fg + 0][sc];
    v.y = tile[4 * fg + 1][sc];
    v.z = tile[4 * fg + 2][sc];
    v.w = tile[4 * fg + 3][sc];
    reinterpret_cast<float4*>(dst)[n] = v;
  }
}

extern "C" void kernel_launch(void* const* d_in, const int* in_sizes, int n_in,
                              void* d_out, int out_size, void* d_ws, size_t ws_size,
                              hipStream_t stream) {
  (void)in_sizes; (void)n_in; (void)out_size; (void)ws_size;
  const float* x = (const float*)d_in[0];
  float* out = (float*)d_out;
  float* ws  = (float*)d_ws;   // needs 2048*8192*4 = 64 MB

  const dim3 gT(S0LEN / 256, 32);
  hipLaunchKernelGGL(k_transpose_fwd, gT, dim3(NTT), 0, stream, x, ws);
  hipLaunchKernelGGL(k_denoise, dim3(NROWS), dim3(NT2), 0, stream, ws);
  hipLaunchKernelGGL(k_transpose_bwd, gT, dim3(NTT), 0, stream, ws, out);
}